// Round 4
// baseline (273.449 us; speedup 1.0000x reference)
//
#include <hip/hip_runtime.h>
#include <cstdint>
#include <cstddef>

typedef unsigned long long ull;

#define KTOP   1000
#define CAP    4096      // candidate gather capacity per (b,c)
#define HBITS  14
#define HSHIFT (32 - HBITS)
#define NB2    512       // histogram window: top-14-bit bins [BLO, BLO+NB2)
#define BLO    3584      // window floor = 3584<<18 = 3.05e-5; all scores >= cth=0.05 land in-window
#define ROWS   1024      // padded rank capacity (>= KTOP)
#define WORDS  16        // 1024 / 64 keep-mask words
#define HCH4   2048      // hist chunk (float4-aligned: 2048*4B = 16B-aligned block starts)
#define GSTAGE 4096      // gather LDS staging capacity (>= per-block chunk)

// ---------------- Kernel 1: softmax scores + hist/cnt zeroing ----------------
__global__ void decode_kernel(const float* __restrict__ conf,
                              float* __restrict__ scores,   // [B*Cfg][P]
                              unsigned* __restrict__ histz, // hist+cnt region to zero
                              int histW,
                              int B, int C, int P) {
#pragma clang fp contract(off)
    int t = blockIdx.x * blockDim.x + threadIdx.x;

    for (int i = t; i < histW; i += gridDim.x * blockDim.x) histz[i] = 0u;

    if (t >= B * P) return;
    int b = t / P;
    int p = t - b * P;

    float x[8];
    float m = -INFINITY;
    for (int c = 0; c < C; ++c) {
        x[c] = conf[((size_t)b * C + c) * P + p];
        m = fmaxf(m, x[c]);
    }
    float sum = 0.f;
    for (int c = 0; c < C; ++c) {
        x[c] = expf(x[c] - m);
        sum += x[c];
    }
    for (int c = 1; c < C; ++c) {
        float v = x[c] / sum;
        int bc = b * (C - 1) + (c - 1);
        scores[(size_t)bc * P + p] = v;
    }
}

// ---------------- Kernel 2: windowed LDS score histogram (float4 loads) ----------------
__global__ void __launch_bounds__(256)
hist_kernel(const float* __restrict__ scores,
            const float* __restrict__ cthp,
            unsigned* __restrict__ hist,     // [NBC][NB2]
            int P) {
    __shared__ unsigned sh[NB2 / 2];         // 1 KB (16-bit packed counters)
    int bc  = blockIdx.x;
    int tid = threadIdx.x;
    float cth = *cthp;

    sh[tid] = 0u;
    __syncthreads();

    int lo = blockIdx.y * HCH4;
    int hi = lo + HCH4; if (hi > P) hi = P;
    const float* s = scores + (size_t)bc * P;
    const float4* s4 = (const float4*)(s + lo);   // lo is 2048-aligned -> 16B aligned
    int n4 = (hi - lo) >> 2;
    for (int i = tid; i < n4; i += 256) {
        float4 v4 = s4[i];
        float vv[4] = {v4.x, v4.y, v4.z, v4.w};
        #pragma unroll
        for (int e = 0; e < 4; ++e) {
            float v = vv[e];
            if (v >= cth) {
                int bl = (int)(__float_as_uint(v) >> HSHIFT) - BLO;
                if (bl < 0) bl = 0;
                atomicAdd(&sh[bl >> 1], (bl & 1) ? 65536u : 1u);
            }
        }
    }
    int tl = lo + (n4 << 2);                 // scalar tail (only if P % 4 != 0)
    for (int p = tl + tid; p < hi; p += 256) {
        float v = s[p];
        if (v >= cth) {
            int bl = (int)(__float_as_uint(v) >> HSHIFT) - BLO;
            if (bl < 0) bl = 0;
            atomicAdd(&sh[bl >> 1], (bl & 1) ? 65536u : 1u);
        }
    }
    __syncthreads();

    unsigned* h = hist + (size_t)bc * NB2;
    unsigned v = sh[tid];
    if (v & 0xFFFFu)  atomicAdd(&h[2 * tid],     v & 0xFFFFu);
    if (v >> 16)      atomicAdd(&h[2 * tid + 1], v >> 16);
}

// ---------------- Kernel 3: inline pivot (wave-level scan) + single-pass gather ----------------
__global__ void __launch_bounds__(256)
gather_kernel(const float* __restrict__ scores,
              const unsigned* __restrict__ hist,
              unsigned* __restrict__ pivot,
              unsigned* __restrict__ cnt,
              ull* __restrict__ cand,
              const float* __restrict__ cthp, int P) {
    __shared__ ull stage[GSTAGE];            // 32 KB
    __shared__ unsigned wpart[4];
    __shared__ unsigned s_pv, l_cnt, s_base;
    int bc = blockIdx.x;
    int tid  = threadIdx.x;
    int wv   = tid >> 6;
    int lane = tid & 63;
    const float* s = scores + (size_t)bc * P;
    float cth = *cthp;

    // ---- pivot: wave-level suffix scan over the 512-bin window (2 barriers) ----
    const unsigned* h = hist + (size_t)bc * NB2;
    unsigned s0 = h[2 * tid], s1 = h[2 * tid + 1];
    unsigned v = s0 + s1;
    if (tid == 0) { s_pv = 0u; l_cnt = 0u; }
    #pragma unroll
    for (int d = 1; d < 64; d <<= 1) {
        unsigned y = (unsigned)__shfl_down((int)v, d);
        if (lane + d < 64) v += y;
    }
    if (lane == 0) wpart[wv] = v;
    __syncthreads();
    unsigned carry = 0;
    for (int w2 = wv + 1; w2 < 4; ++w2) carry += wpart[w2];
    unsigned St = v + carry;                 // cnt(bin >= 2*tid)
    if (St >= (unsigned)KTOP && (St - s0 - s1) < (unsigned)KTOP) {
        unsigned pl = (St - s0 >= (unsigned)KTOP) ? (2u * tid + 1u) : (2u * tid);
        s_pv = pl + (unsigned)BLO;
    }
    __syncthreads();
    unsigned pv = s_pv;
    if (pv <= (unsigned)BLO) pv = 0u;        // fallback: take all >= cth
    if (blockIdx.y == 0 && tid == 0) pivot[bc] = pv;

    // ---- single-pass gather: ballot-aggregated LDS staging, one global atomic ----
    int nchunk = gridDim.y;
    int chunk = (P + nchunk - 1) / nchunk;   // <= GSTAGE by launcher construction
    int lo = blockIdx.y * chunk;
    int hi = lo + chunk; if (hi > P) hi = P;

    for (int p0 = lo; p0 < hi; p0 += 256) {
        int p = p0 + tid;
        bool q = false; unsigned k = 0u;
        if (p < hi) {
            float vs = s[p];
            k = __float_as_uint(vs);
            q = (vs >= cth) && ((k >> HSHIFT) >= pv);
        }
        ull mb = __ballot(q);
        if (mb) {
            unsigned wbase = 0u;
            if (lane == 0) wbase = atomicAdd(&l_cnt, (unsigned)__popcll(mb));
            wbase = (unsigned)__shfl((int)wbase, 0);
            if (q) {
                unsigned pos = wbase + (unsigned)__popcll(mb & ((1ull << lane) - 1ull));
                stage[pos] = ((ull)k << 32) | (unsigned)(~(unsigned)p);
            }
        }
    }
    __syncthreads();

    unsigned tot = l_cnt;
    if (tid == 0) s_base = tot ? atomicAdd(&cnt[bc], tot) : 0u;
    __syncthreads();
    unsigned base = s_base;
    ull* cb = cand + (size_t)bc * CAP;
    for (unsigned i = tid; i < tot; i += 256) {
        unsigned off = base + i;
        if (off < CAP) cb[off] = stage[i];
    }
}

// ---------------- Kernel 4: refine + RANK-SCATTER (no sort) + fused mask ----------------
// Keys are unique (low 32 bits = ~p), so rank = #{keys > mine} is a permutation:
// each thread counts via wave-broadcast LDS reads — ZERO barriers vs 55 bitonic
// passes — then scatters its decoded box to SoA LDS at `rank` and its output row
// to global. The mask triangle then runs from LDS (pbox/bar round-trip and the
// separate mask launch are gone). reduce_pack (proven) is unchanged.
__global__ void __launch_bounds__(1024)
rankmask_kernel(const ull* __restrict__ cand,
                const unsigned* __restrict__ cnt,
                const unsigned* __restrict__ pivot,
                const float* __restrict__ loc,
                const float* __restrict__ prior,
                const float* __restrict__ nthp,
                float* __restrict__ rows,      // [NBC][KTOP][5]
                ull* __restrict__ mask,        // [NBC][ROWS][WORDS]
                int* __restrict__ nselArr,
                int P, int Cfg) {
#pragma clang fp contract(off)
    int bc  = blockIdx.x;
    int b   = bc / Cfg;
    int tid = threadIdx.x;
    int wv   = tid >> 6;
    int lane = tid & 63;

    __shared__ ull      sbuf[CAP];        // 32 KB candidate keys
    __shared__ unsigned h2[1024];         // 4 KB refine histogram
    __shared__ float sx1[ROWS], sy1[ROWS], sx2[ROWS], sy2[ROWS], sar[ROWS]; // 20 KB SoA
    __shared__ unsigned wpart[16], wcarry[16];
    __shared__ unsigned s_hi, s_spv, s_m2, s_pos;

    float nth = *nthp;
    int M = (int)cnt[bc]; if (M > CAP) M = CAP;
    int nsel = M < KTOP ? M : KTOP;
    if (tid == 0) nselArr[bc] = nsel;

    for (int i = tid; i < M; i += 1024)
        sbuf[i] = cand[(size_t)bc * CAP + i];
    for (int i = tid; i < ROWS; i += 1024)     // deterministic zero boxes for slots >= nsel
        if (i >= nsel) { sx1[i] = 0.f; sy1[i] = 0.f; sx2[i] = 0.f; sy2[i] = 0.f; sar[i] = 0.f; }
    __syncthreads();

    // ---- refine: cut M (<=4096) to Meff (~KTOP) via 10-bit sub-bin histogram ----
    int Meff = M;
    if (M > 1024) {
        unsigned pv = pivot[bc];
        h2[tid] = 0u;
        if (tid == 0) { s_hi = 0u; s_pos = 0u; s_spv = 0u; s_m2 = (unsigned)M; }
        __syncthreads();
        for (int i = tid; i < M; i += 1024) {
            unsigned sb32 = (unsigned)(sbuf[i] >> 32);
            if ((sb32 >> HSHIFT) > pv) atomicAdd(&s_hi, 1u);
            else atomicAdd(&h2[(sb32 >> 8) & 1023u], 1u);   // bin == pv (gather guarantee)
        }
        __syncthreads();
        unsigned hicnt = s_hi;               // < KTOP by pivot construction
        // wave-level suffix scan over 1024 bins (16 waves): 2 barriers vs 20
        unsigned h0 = h2[tid];
        unsigned v = h0;
        #pragma unroll
        for (int d = 1; d < 64; d <<= 1) {
            unsigned y = (unsigned)__shfl_down((int)v, d);
            if (lane + d < 64) v += y;
        }
        if (lane == 0) wpart[wv] = v;
        __syncthreads();
        if (tid < 16) {
            unsigned c2 = 0;
            for (int w2 = tid + 1; w2 < 16; ++w2) c2 += wpart[w2];
            wcarry[tid] = c2;
        }
        __syncthreads();
        unsigned A  = hicnt + v + wcarry[wv];   // cnt(sub-bin >= tid) incl. higher bins
        unsigned Bv = A - h0;                    // cnt(sub-bin >= tid+1)
        if (A >= (unsigned)KTOP && Bv < (unsigned)KTOP) { s_spv = (unsigned)tid; s_m2 = A; }
        __syncthreads();
        unsigned thr24 = ((unsigned)pv << 10) | s_spv;      // top-24-bit threshold
        Meff = (int)s_m2;
        ull my[CAP / 1024];                  // read-all / barrier / write: in-place compact
        #pragma unroll
        for (int j = 0; j < CAP / 1024; ++j) { int i = tid + (j << 10); my[j] = (i < M) ? sbuf[i] : 0ull; }
        __syncthreads();
        #pragma unroll
        for (int j = 0; j < CAP / 1024; ++j) {
            int i = tid + (j << 10);
            if (i < M && (unsigned)(my[j] >> 40) >= thr24) {
                unsigned pos = atomicAdd(&s_pos, 1u);
                sbuf[pos] = my[j];
            }
        }
        __syncthreads();
    }

    // ---- rank-scatter: rank = #{keys > mine}; barrier-free broadcast scan ----
    for (int i = tid; i < Meff; i += 1024) {
        ull key = sbuf[i];
        int rank = 0;
        int j = 0;
        for (; j + 4 <= Meff; j += 4) {
            rank += (sbuf[j]     > key);
            rank += (sbuf[j + 1] > key);
            rank += (sbuf[j + 2] > key);
            rank += (sbuf[j + 3] > key);
        }
        for (; j < Meff; ++j) rank += (sbuf[j] > key);
        if (rank < nsel) {
            float sc = __uint_as_float((unsigned)(key >> 32));
            int idx = (int)(~(unsigned)key);
            // SSD decode, bit-identical to the reference expression (contract off)
            float l0 = loc[((size_t)b * 4 + 0) * P + idx];
            float l1 = loc[((size_t)b * 4 + 1) * P + idx];
            float l2 = loc[((size_t)b * 4 + 2) * P + idx];
            float l3 = loc[((size_t)b * 4 + 3) * P + idx];
            float4 pr4 = *(const float4*)(prior + (size_t)idx * 4);
            float cx = pr4.x + (l0 * 0.1f) * pr4.z;
            float cy = pr4.y + (l1 * 0.1f) * pr4.w;
            float w  = pr4.z * expf(l2 * 0.2f);
            float h  = pr4.w * expf(l3 * 0.2f);
            float x1 = cx - w / 2.f, y1 = cy - h / 2.f;
            float x2 = cx + w / 2.f, y2 = cy + h / 2.f;
            sx1[rank] = x1; sy1[rank] = y1; sx2[rank] = x2; sy2[rank] = y2;
            sar[rank] = fmaxf(x2 - x1, 0.f) * fmaxf(y2 - y1, 0.f);
            float* rr = rows + ((size_t)bc * KTOP + rank) * 5;
            rr[0] = sc; rr[1] = cx; rr[2] = cy; rr[3] = w; rr[4] = h;
        }
    }
    __syncthreads();

    // ---- fused suppression mask from LDS SoA (upper-triangle, load-balanced) ----
    int whi = (nsel + 63) >> 6;              // words/tiles in use
    for (int k2 = wv; k2 < whi * 16; k2 += 16) {   // items (tile t, row-group rg)
        int t  = k2 >> 4;
        int rg = k2 & 15;
        int i0 = (t << 6) + (rg << 2);
        float bx1[4], by1[4], bx2[4], by2[4], ba[4];
        #pragma unroll
        for (int r = 0; r < 4; ++r) {
            bx1[r] = sx1[i0 + r]; by1[r] = sy1[i0 + r];
            bx2[r] = sx2[i0 + r]; by2[r] = sy2[i0 + r]; ba[r] = sar[i0 + r];
        }
        ull rowbits[4] = {0ull, 0ull, 0ull, 0ull};
        for (int w = t; w < whi; ++w) {
            int j = (w << 6) + lane;
            float jx1 = sx1[j], jy1 = sy1[j], jx2 = sx2[j], jy2 = sy2[j], ja = sar[j];
            #pragma unroll
            for (int r = 0; r < 4; ++r) {
                int i = i0 + r;
                float ww = fmaxf(fminf(bx2[r], jx2) - fmaxf(bx1[r], jx1), 0.f);
                float hh = fmaxf(fminf(by2[r], jy2) - fmaxf(by1[r], jy1), 0.f);
                float inter = ww * hh;
                float uni = ba[r] + ja - inter;
                float iou = inter / fmaxf(uni, 1e-12f);
                bool ok = (j > i) && (j < nsel) && (iou > nth);
                ull bits = __ballot(ok);
                if (lane == w) rowbits[r] = bits;
            }
        }
        #pragma unroll
        for (int r = 0; r < 4; ++r)
            if (lane < WORDS)
                mask[(((size_t)bc * ROWS + (i0 + r)) << 4) + lane] = rowbits[r];
    }
}

// ---------------- Kernel 5: fused serial reduce + parallel pack (unchanged, proven) ----------------
__device__ __forceinline__ void nms_chunk_body(
    int c, int nchunk, int lane, int g, int w,
    const ull* __restrict__ mrow, ull* sm,
    ull (&pr)[16], ull (&st)[16], ull& S)
{
    int cb = (c & 1) << 10;
    int nb = ((c + 1) & 1) << 10;
    if (c + 2 < nchunk) {                    // prefetch chunk c+2 from global
        #pragma unroll
        for (int k = 0; k < 16; ++k)
            pr[k] = mrow[(size_t)(c + 2) * 1024 + k * 64 + lane];
    }

    // ---- serial greedy on word c: register-fed, group-pipelined ----
    ull cur = __shfl(S, c);
    ull dbuf[16], dnxt[16];
    #pragma unroll
    for (int k = 0; k < 16; ++k) dbuf[k] = sm[cb + (k << 4) + c];   // group 0
    #pragma unroll
    for (int grp = 0; grp < 4; ++grp) {
        if (grp < 3) {                       // issue group grp+1 reads (independent)
            #pragma unroll
            for (int k = 0; k < 16; ++k)
                dnxt[k] = sm[cb + ((((grp + 1) << 4) + k) << 4) + c];
        }
        #pragma unroll
        for (int k = 0; k < 16; ++k) {       // pure-VALU serial steps
            int i = (grp << 4) + k;
            ull supm = (ull)((long long)(cur << (63 - i)) >> 63);   // all-ones iff rank i suppressed
            cur |= dbuf[k] & ~supm;
        }
        if (grp < 3) {
            #pragma unroll
            for (int k = 0; k < 16; ++k) dbuf[k] = dnxt[k];
        }
    }
    ull kbits = ~cur;                        // kept = not suppressed

    // ---- bulk apply: lane (g,w) ORs kept rows of group g, word w ----
    unsigned sub = (unsigned)((kbits >> (g << 4)) & 0xFFFFull);
    int rbase2 = cb + (g << 8) + w;
    ull part = 0ull;
    #pragma unroll
    for (int i = 0; i < 16; ++i) {
        ull v = sm[rbase2 + (i << 4)];       // unconditional, pipelined
        part |= v & (ull)(0ll - (long long)((sub >> i) & 1u));
    }
    part |= __shfl_xor(part, 16);
    part |= __shfl_xor(part, 32);
    S |= part;                               // lanes 0..15 meaningful
    if (lane == c) S = cur;                  // finalize word c

    if (c + 1 < nchunk) {                    // stage chunk c+1 into the other LDS buffer
        #pragma unroll
        for (int k = 0; k < 16; ++k) sm[nb + k * 64 + lane] = st[k];
    }
}

__global__ void __launch_bounds__(256)
reduce_pack_kernel(const ull* __restrict__ mask,
                   const int* __restrict__ nselArr,
                   const float* __restrict__ rows,
                   float* __restrict__ out) {
    int bc  = blockIdx.x;
    int tid = threadIdx.x;
    int nsel = nselArr[bc];
    const ull* mrow = mask + ((size_t)bc * ROWS << 4);

    __shared__ ull sm[2048];                // 2 x (64 rows x 16 words) = 16 KB
    __shared__ ull kw[WORDS];
    __shared__ unsigned pref[WORDS + 1];

    if (tid < 64) {                          // wave 0: serial reduce
        int lane = tid;
        int nchunk = (nsel + 63) >> 6;       // <= 16
        ull S = 0ull;
        int g = lane >> 4;
        int w = lane & 15;

        ull ra[16], rb[16];
        if (nchunk > 0) {
            #pragma unroll
            for (int k = 0; k < 16; ++k) ra[k] = mrow[k * 64 + lane];
            if (nchunk > 1) {
                #pragma unroll
                for (int k = 0; k < 16; ++k) rb[k] = mrow[1024 + k * 64 + lane];
            }
            #pragma unroll
            for (int k = 0; k < 16; ++k) sm[k * 64 + lane] = ra[k];

            #pragma unroll 1
            for (int cc = 0; cc < 8; ++cc) {
                int c0 = cc << 1;
                if (c0 >= nchunk) break;
                nms_chunk_body(c0, nchunk, lane, g, w, mrow, sm, ra, rb, S);
                int c1 = c0 + 1;
                if (c1 >= nchunk) break;
                nms_chunk_body(c1, nchunk, lane, g, w, mrow, sm, rb, ra, S);
            }
        }

        if (lane < WORDS) {
            int base_i = lane << 6;
            ull valid = 0ull;
            int rem = nsel - base_i;
            if (rem > 0) valid = (rem >= 64) ? ~0ull : ((1ull << rem) - 1ull);
            kw[lane] = (~S) & valid;
        }
    }
    __syncthreads();

    if (tid == 0) {
        unsigned c = 0;
        for (int w = 0; w < WORDS; ++w) { pref[w] = c; c += (unsigned)__popcll(kw[w]); }
        pref[WORDS] = c;
    }
    __syncthreads();
    unsigned tot = pref[WORDS];

    const float* rbase = rows + (size_t)bc * KTOP * 5;
    float* obase = out + (size_t)bc * KTOP * 5;
    for (int r = tid; r < KTOP; r += 256) {
        ull wv = kw[r >> 6];
        if ((wv >> (r & 63)) & 1ull) {
            int pos = (int)pref[r >> 6] + __popcll(wv & ((1ull << (r & 63)) - 1ull));
            const float* rr = rbase + r * 5;
            float* oo = obase + pos * 5;
            oo[0] = rr[0]; oo[1] = rr[1]; oo[2] = rr[2]; oo[3] = rr[3]; oo[4] = rr[4];
        }
        if (r >= (int)tot) {                 // zero-fill tail (replaces out memset)
            float* oo = obase + r * 5;
            oo[0] = 0.f; oo[1] = 0.f; oo[2] = 0.f; oo[3] = 0.f; oo[4] = 0.f;
        }
    }
}

// ------------------------------- launcher -------------------------------
extern "C" void kernel_launch(void* const* d_in, const int* in_sizes, int n_in,
                              void* d_out, int out_size, void* d_ws, size_t ws_size,
                              hipStream_t stream) {
    (void)n_in; (void)out_size; (void)ws_size;
    const float* loc   = (const float*)d_in[0];
    const float* conf  = (const float*)d_in[1];
    const float* prior = (const float*)d_in[2];
    const float* cth   = (const float*)d_in[3];
    const float* nth   = (const float*)d_in[4];
    float* out = (float*)d_out;

    int P   = in_sizes[2] / 4;
    int B   = in_sizes[0] / (4 * P);
    int C   = in_sizes[1] / (B * P);
    int Cfg = C - 1;
    int NBC = B * Cfg;

    // ---- carve workspace (256B aligned sections; widest types first) ----
    char* base = (char*)d_ws;
    size_t off = 0;
    auto carve = [&](size_t bytes) { char* p = base + off; off = (off + bytes + 255) & ~(size_t)255; return p; };

    ull*      cand   = (ull*)     carve((size_t)NBC * CAP * 8);
    ull*      mask   = (ull*)     carve((size_t)NBC * ROWS * WORDS * 8);
    float*    scores = (float*)   carve((size_t)NBC * P * 4);
    float*    rows   = (float*)   carve((size_t)NBC * KTOP * 5 * 4);
    unsigned* hist   = (unsigned*)carve((size_t)NBC * NB2 * 4 + (size_t)NBC * 4); // hist + cnt
    unsigned* cnt    = hist + (size_t)NBC * NB2;
    unsigned* pivot  = (unsigned*)carve((size_t)NBC * 4);
    int*      nselA  = (int*)     carve((size_t)NBC * 4);

    int histW = NBC * NB2 + NBC;             // words to zero (hist + cnt)

    int GYH = (P + HCH4 - 1) / HCH4;         // hist chunks (float4-aligned starts)
    int GY = (P + GSTAGE - 1) / GSTAGE;      // gather chunks: chunk <= GSTAGE guaranteed
    if (GY < 32) GY = 32;

    int n1 = B * P;
    decode_kernel<<<(n1 + 255) / 256, 256, 0, stream>>>(conf, scores, hist, histW, B, C, P);
    hist_kernel<<<dim3(NBC, GYH), 256, 0, stream>>>(scores, cth, hist, P);
    gather_kernel<<<dim3(NBC, GY), 256, 0, stream>>>(scores, hist, pivot, cnt, cand, cth, P);
    rankmask_kernel<<<NBC, 1024, 0, stream>>>(cand, cnt, pivot, loc, prior, nth, rows, mask, nselA, P, Cfg);
    reduce_pack_kernel<<<NBC, 256, 0, stream>>>(mask, nselA, rows, out);
}

// Round 5
// 179.559 us; speedup vs baseline: 1.5229x; 1.5229x over previous
//
#include <hip/hip_runtime.h>
#include <cstdint>
#include <cstddef>

typedef unsigned long long ull;

#define KTOP   1000
#define CAP    4096      // candidate gather capacity per (b,c)
#define HBITS  14
#define HSHIFT (32 - HBITS)
#define NB2    512       // histogram window: top-14-bit bins [BLO, BLO+NB2)
#define BLO    3584      // window floor = 3584<<18 = 3.05e-5; all scores >= cth=0.05 land in-window
#define ROWS   1024      // padded rank capacity (>= KTOP)
#define WORDS  16        // 1024 / 64 bitmask words per row
#define HCH4   2048      // hist chunk (float4-aligned block starts)
#define GSTAGE 4096      // gather LDS staging capacity (>= per-block chunk)

// ---------------- Kernel 1: softmax scores + hist/cnt zeroing (R2 proven) ----------------
__global__ void decode_kernel(const float* __restrict__ conf,
                              float* __restrict__ scores,   // [B*Cfg][P]
                              unsigned* __restrict__ histz, // hist+cnt region to zero
                              int histW,
                              int B, int C, int P) {
#pragma clang fp contract(off)
    int t = blockIdx.x * blockDim.x + threadIdx.x;

    for (int i = t; i < histW; i += gridDim.x * blockDim.x) histz[i] = 0u;

    if (t >= B * P) return;
    int b = t / P;
    int p = t - b * P;

    float x[8];
    float m = -INFINITY;
    for (int c = 0; c < C; ++c) {
        x[c] = conf[((size_t)b * C + c) * P + p];
        m = fmaxf(m, x[c]);
    }
    float sum = 0.f;
    for (int c = 0; c < C; ++c) {
        x[c] = expf(x[c] - m);
        sum += x[c];
    }
    for (int c = 1; c < C; ++c) {
        float v = x[c] / sum;
        int bc = b * (C - 1) + (c - 1);
        scores[(size_t)bc * P + p] = v;
    }
}

// ---------------- Kernel 2: windowed LDS score histogram, float4 loads (validated R4) ----------------
__global__ void __launch_bounds__(256)
hist_kernel(const float* __restrict__ scores,
            const float* __restrict__ cthp,
            unsigned* __restrict__ hist,     // [NBC][NB2]
            int P) {
    __shared__ unsigned sh[NB2 / 2];         // 1 KB (16-bit packed counters)
    int bc  = blockIdx.x;
    int tid = threadIdx.x;
    float cth = *cthp;

    sh[tid] = 0u;
    __syncthreads();

    int lo = blockIdx.y * HCH4;
    int hi = lo + HCH4; if (hi > P) hi = P;
    const float* s = scores + (size_t)bc * P;
    const float4* s4 = (const float4*)(s + lo);   // lo is 2048-aligned -> 16B aligned
    int n4 = (hi - lo) >> 2;
    for (int i = tid; i < n4; i += 256) {
        float4 v4 = s4[i];
        float vv[4] = {v4.x, v4.y, v4.z, v4.w};
        #pragma unroll
        for (int e = 0; e < 4; ++e) {
            float v = vv[e];
            if (v >= cth) {
                int bl = (int)(__float_as_uint(v) >> HSHIFT) - BLO;
                if (bl < 0) bl = 0;
                atomicAdd(&sh[bl >> 1], (bl & 1) ? 65536u : 1u);
            }
        }
    }
    int tl = lo + (n4 << 2);                 // scalar tail (only if P % 4 != 0)
    for (int p = tl + tid; p < hi; p += 256) {
        float v = s[p];
        if (v >= cth) {
            int bl = (int)(__float_as_uint(v) >> HSHIFT) - BLO;
            if (bl < 0) bl = 0;
            atomicAdd(&sh[bl >> 1], (bl & 1) ? 65536u : 1u);
        }
    }
    __syncthreads();

    unsigned* h = hist + (size_t)bc * NB2;
    unsigned v = sh[tid];
    if (v & 0xFFFFu)  atomicAdd(&h[2 * tid],     v & 0xFFFFu);
    if (v >> 16)      atomicAdd(&h[2 * tid + 1], v >> 16);
}

// ---------------- Kernel 3: wave-scan pivot + single-pass gather (validated R4) ----------------
__global__ void __launch_bounds__(256)
gather_kernel(const float* __restrict__ scores,
              const unsigned* __restrict__ hist,
              unsigned* __restrict__ pivot,
              unsigned* __restrict__ cnt,
              ull* __restrict__ cand,
              const float* __restrict__ cthp, int P) {
    __shared__ ull stage[GSTAGE];            // 32 KB
    __shared__ unsigned wpart[4];
    __shared__ unsigned s_pv, l_cnt, s_base;
    int bc = blockIdx.x;
    int tid  = threadIdx.x;
    int wv   = tid >> 6;
    int lane = tid & 63;
    const float* s = scores + (size_t)bc * P;
    float cth = *cthp;

    // ---- pivot: wave-level suffix scan over the 512-bin window (2 barriers) ----
    const unsigned* h = hist + (size_t)bc * NB2;
    unsigned s0 = h[2 * tid], s1 = h[2 * tid + 1];
    unsigned v = s0 + s1;
    if (tid == 0) { s_pv = 0u; l_cnt = 0u; }
    #pragma unroll
    for (int d = 1; d < 64; d <<= 1) {
        unsigned y = (unsigned)__shfl_down((int)v, d);
        if (lane + d < 64) v += y;
    }
    if (lane == 0) wpart[wv] = v;
    __syncthreads();
    unsigned carry = 0;
    for (int w2 = wv + 1; w2 < 4; ++w2) carry += wpart[w2];
    unsigned St = v + carry;                 // cnt(bin >= 2*tid)
    if (St >= (unsigned)KTOP && (St - s0 - s1) < (unsigned)KTOP) {
        unsigned pl = (St - s0 >= (unsigned)KTOP) ? (2u * tid + 1u) : (2u * tid);
        s_pv = pl + (unsigned)BLO;
    }
    __syncthreads();
    unsigned pv = s_pv;
    if (pv <= (unsigned)BLO) pv = 0u;        // fallback: take all >= cth
    if (blockIdx.y == 0 && tid == 0) pivot[bc] = pv;

    // ---- single-pass gather: ballot-aggregated LDS staging, one global atomic ----
    int nchunk = gridDim.y;
    int chunk = (P + nchunk - 1) / nchunk;   // <= GSTAGE by launcher construction
    int lo = blockIdx.y * chunk;
    int hi = lo + chunk; if (hi > P) hi = P;

    for (int p0 = lo; p0 < hi; p0 += 256) {
        int p = p0 + tid;
        bool q = false; unsigned k = 0u;
        if (p < hi) {
            float vs = s[p];
            k = __float_as_uint(vs);
            q = (vs >= cth) && ((k >> HSHIFT) >= pv);
        }
        ull mb = __ballot(q);
        if (mb) {
            unsigned wbase = 0u;
            if (lane == 0) wbase = atomicAdd(&l_cnt, (unsigned)__popcll(mb));
            wbase = (unsigned)__shfl((int)wbase, 0);
            if (q) {
                unsigned pos = wbase + (unsigned)__popcll(mb & ((1ull << lane) - 1ull));
                stage[pos] = ((ull)k << 32) | (unsigned)(~(unsigned)p);
            }
        }
    }
    __syncthreads();

    unsigned tot = l_cnt;
    if (tid == 0) s_base = tot ? atomicAdd(&cnt[bc], tot) : 0u;
    __syncthreads();
    unsigned base = s_base;
    ull* cb = cand + (size_t)bc * CAP;
    for (unsigned i = tid; i < tot; i += 256) {
        unsigned off = base + i;
        if (off < CAP) cb[off] = stage[i];
    }
}

// ---------------- Kernel 4: radix-refine (wave-scan) + bitonic sort + decode/export ----------------
// R2 structure (proven); refine scan switched to wave-shfl (3 barriers vs 20, validated R4).
__global__ void __launch_bounds__(1024)
sort_kernel(const ull* __restrict__ cand,
            const unsigned* __restrict__ cnt,
            const unsigned* __restrict__ pivot,
            const float* __restrict__ loc,
            const float* __restrict__ prior,
            float* __restrict__ rows,      // [NBC][KTOP][5] score,cx,cy,w,h
            float4* __restrict__ pbox,     // [NBC][ROWS] point-form x1,y1,x2,y2
            float* __restrict__ bar,       // [NBC][ROWS] area
            int* __restrict__ nselArr,
            int P, int Cfg) {
#pragma clang fp contract(off)
    int bc  = blockIdx.x;
    int b   = bc / Cfg;
    int tid = threadIdx.x;
    int wv   = tid >> 6;
    int lane = tid & 63;
    __shared__ ull sbuf[CAP];                // 32 KB
    __shared__ unsigned h2[1024];            // 4 KB refine histogram
    __shared__ unsigned wpart[16], wcarry[16];
    __shared__ unsigned s_hi, s_spv, s_m2, s_pos;

    int M = (int)cnt[bc]; if (M > CAP) M = CAP;
    int nsel = M < KTOP ? M : KTOP;
    if (tid == 0) nselArr[bc] = nsel;

    for (int i = tid; i < M; i += 1024)
        sbuf[i] = cand[(size_t)bc * CAP + i];
    __syncthreads();

    int Meff = M;
    if (M > 1024) {
        unsigned pv = pivot[bc];
        h2[tid] = 0u;
        if (tid == 0) { s_hi = 0u; s_pos = 0u; s_spv = 0u; s_m2 = (unsigned)M; } // safe fallback
        __syncthreads();
        for (int i = tid; i < M; i += 1024) {
            unsigned sb32 = (unsigned)(sbuf[i] >> 32);
            if ((sb32 >> HSHIFT) > pv) atomicAdd(&s_hi, 1u);
            else atomicAdd(&h2[(sb32 >> 8) & 1023u], 1u);   // bin == pv (gather guarantee)
        }
        __syncthreads();
        unsigned hicnt = s_hi;               // < KTOP by pivot construction
        // wave-level suffix scan over 1024 sub-bins (16 waves, 3 barriers)
        unsigned h0 = h2[tid];
        unsigned v = h0;
        #pragma unroll
        for (int d = 1; d < 64; d <<= 1) {
            unsigned y = (unsigned)__shfl_down((int)v, d);
            if (lane + d < 64) v += y;
        }
        if (lane == 0) wpart[wv] = v;
        __syncthreads();
        if (tid < 16) {
            unsigned c2 = 0;
            for (int w2 = tid + 1; w2 < 16; ++w2) c2 += wpart[w2];
            wcarry[tid] = c2;
        }
        __syncthreads();
        unsigned A  = hicnt + v + wcarry[wv];   // cnt(key-subbin >= tid) incl. higher bins
        unsigned Bv = A - h0;                    // cnt(key-subbin >= tid+1)
        if (A >= (unsigned)KTOP && Bv < (unsigned)KTOP) { s_spv = (unsigned)tid; s_m2 = A; }
        __syncthreads();
        unsigned thr24 = ((unsigned)pv << 10) | s_spv;      // top-24-bit threshold
        Meff = (int)s_m2;
        ull my[CAP / 1024];                  // read-all / barrier / write: in-place compact
        #pragma unroll
        for (int j = 0; j < CAP / 1024; ++j) { int i = tid + (j << 10); my[j] = (i < M) ? sbuf[i] : 0ull; }
        __syncthreads();
        #pragma unroll
        for (int j = 0; j < CAP / 1024; ++j) {
            int i = tid + (j << 10);
            if (i < M && (unsigned)(my[j] >> 40) >= thr24) {
                unsigned pos = atomicAdd(&s_pos, 1u);
                sbuf[pos] = my[j];
            }
        }
        __syncthreads();
    }

    int n = 1024;
    while (n < Meff) n <<= 1;
    for (int i = tid; i < n; i += 1024)
        if (i >= Meff) sbuf[i] = 0ull;       // real keys are > 0 -> pad sorts last
    __syncthreads();

    for (unsigned k = 2; k <= (unsigned)n; k <<= 1) {
        for (unsigned j = k >> 1; j > 0; j >>= 1) {
            for (unsigned i = tid; i < (unsigned)n; i += 1024) {
                unsigned ixj = i ^ j;
                if (ixj > i) {
                    bool up = ((i & k) == 0u);
                    ull a = sbuf[i], bb = sbuf[ixj];
                    if ((a > bb) == up) { sbuf[i] = bb; sbuf[ixj] = a; }
                }
            }
            __syncthreads();
        }
    }

    for (int r = tid; r < nsel; r += 1024) {
        ull e = sbuf[n - 1 - r];
        float sc = __uint_as_float((unsigned)(e >> 32));
        int idx = (int)(~(unsigned)e);
        // recompute SSD decode (bit-identical to the reference decode expression)
        float l0 = loc[((size_t)b * 4 + 0) * P + idx];
        float l1 = loc[((size_t)b * 4 + 1) * P + idx];
        float l2 = loc[((size_t)b * 4 + 2) * P + idx];
        float l3 = loc[((size_t)b * 4 + 3) * P + idx];
        float4 pr4 = *(const float4*)(prior + (size_t)idx * 4);
        float cx = pr4.x + (l0 * 0.1f) * pr4.z;
        float cy = pr4.y + (l1 * 0.1f) * pr4.w;
        float w  = pr4.z * expf(l2 * 0.2f);
        float h  = pr4.w * expf(l3 * 0.2f);
        float x1 = cx - w / 2.f, y1 = cy - h / 2.f;
        float x2 = cx + w / 2.f, y2 = cy + h / 2.f;
        size_t sb = (size_t)bc * ROWS + r;
        pbox[sb] = make_float4(x1, y1, x2, y2);
        bar[sb]  = fmaxf(x2 - x1, 0.f) * fmaxf(y2 - y1, 0.f);
        float* rr = rows + ((size_t)bc * KTOP + r) * 5;
        rr[0] = sc; rr[1] = cx; rr[2] = cy; rr[3] = w; rr[4] = h;
    }
}

// ---------------- Kernel 5: suppression bitmask, 512 blocks (R2 proven) ----------------
__global__ void __launch_bounds__(1024)
mask_kernel(const float4* __restrict__ pbox,
            const float* __restrict__ bar,
            const int* __restrict__ nselArr,
            const float* __restrict__ nthp,
            ull* __restrict__ mask) {       // [NBC][ROWS][WORDS]
#pragma clang fp contract(off)
    int bc   = blockIdx.x;
    int tile = blockIdx.y;                  // 16 tiles x 64 rows
    int tid  = threadIdx.x;
    int nsel = nselArr[bc];
    float nth = *nthp;

    __shared__ float4 sbox[ROWS];           // 16 KB
    __shared__ float  sar[ROWS];            // 4 KB
    size_t sb = (size_t)bc * ROWS;
    sbox[tid] = pbox[sb + tid];
    sar[tid]  = bar[sb + tid];
    __syncthreads();

    int wv   = tid >> 6;                    // wave 0..15
    int lane = tid & 63;
    int i0   = tile * 64 + (wv << 2);       // 4 rows per wave

    ull rowbits[4] = {0ull, 0ull, 0ull, 0ull};
    if (i0 < nsel) {
        float4 bi[4]; float ai[4];
        #pragma unroll
        for (int r = 0; r < 4; ++r) { bi[r] = sbox[i0 + r]; ai[r] = sar[i0 + r]; }

        int whi = (nsel + 63) >> 6; if (whi > WORDS) whi = WORDS;
        for (int w = tile; w < whi; ++w) {
            int j = (w << 6) + lane;
            float4 bj = sbox[j];
            float  aj = sar[j];
            #pragma unroll
            for (int r = 0; r < 4; ++r) {
                int i = i0 + r;
                float ww = fmaxf(fminf(bi[r].z, bj.z) - fmaxf(bi[r].x, bj.x), 0.f);
                float hh = fmaxf(fminf(bi[r].w, bj.w) - fmaxf(bi[r].y, bj.y), 0.f);
                float inter = ww * hh;
                float uni = ai[r] + aj - inter;
                float iou = inter / fmaxf(uni, 1e-12f);
                bool ok = (j > i) && (j < nsel) && (iou > nth);
                ull bits = __ballot(ok);
                if (lane == w) rowbits[r] = bits;
            }
        }
    }
    #pragma unroll
    for (int r = 0; r < 4; ++r)
        if (lane < WORDS)
            mask[(((size_t)bc * ROWS + (i0 + r)) << 4) + lane] = rowbits[r];
}

// ---------------- Kernel 6: fused serial reduce + parallel pack (R2 proven) ----------------
__device__ __forceinline__ void nms_chunk_body(
    int c, int nchunk, int lane, int g, int w,
    const ull* __restrict__ mrow, ull* sm,
    ull (&pr)[16], ull (&st)[16], ull& S)
{
    int cb = (c & 1) << 10;
    int nb = ((c + 1) & 1) << 10;
    if (c + 2 < nchunk) {                    // prefetch chunk c+2 from global
        #pragma unroll
        for (int k = 0; k < 16; ++k)
            pr[k] = mrow[(size_t)(c + 2) * 1024 + k * 64 + lane];
    }

    // ---- serial greedy on word c: register-fed, group-pipelined ----
    ull cur = __shfl(S, c);
    ull dbuf[16], dnxt[16];
    #pragma unroll
    for (int k = 0; k < 16; ++k) dbuf[k] = sm[cb + (k << 4) + c];   // group 0
    #pragma unroll
    for (int grp = 0; grp < 4; ++grp) {
        if (grp < 3) {                       // issue group grp+1 reads (independent)
            #pragma unroll
            for (int k = 0; k < 16; ++k)
                dnxt[k] = sm[cb + ((((grp + 1) << 4) + k) << 4) + c];
        }
        #pragma unroll
        for (int k = 0; k < 16; ++k) {       // pure-VALU serial steps
            int i = (grp << 4) + k;
            ull supm = (ull)((long long)(cur << (63 - i)) >> 63);   // all-ones iff rank i suppressed
            cur |= dbuf[k] & ~supm;
        }
        if (grp < 3) {
            #pragma unroll
            for (int k = 0; k < 16; ++k) dbuf[k] = dnxt[k];
        }
    }
    ull kbits = ~cur;                        // kept = not suppressed

    // ---- bulk apply: lane (g,w) ORs kept rows of group g, word w ----
    unsigned sub = (unsigned)((kbits >> (g << 4)) & 0xFFFFull);
    int rbase2 = cb + (g << 8) + w;
    ull part = 0ull;
    #pragma unroll
    for (int i = 0; i < 16; ++i) {
        ull v = sm[rbase2 + (i << 4)];       // unconditional, pipelined
        part |= v & (ull)(0ll - (long long)((sub >> i) & 1u));
    }
    part |= __shfl_xor(part, 16);
    part |= __shfl_xor(part, 32);
    S |= part;                               // lanes 0..15 meaningful
    if (lane == c) S = cur;                  // finalize word c

    if (c + 1 < nchunk) {                    // stage chunk c+1 into the other LDS buffer
        #pragma unroll
        for (int k = 0; k < 16; ++k) sm[nb + k * 64 + lane] = st[k];
    }
}

__global__ void __launch_bounds__(256)
reduce_pack_kernel(const ull* __restrict__ mask,
                   const int* __restrict__ nselArr,
                   const float* __restrict__ rows,
                   float* __restrict__ out) {
    int bc  = blockIdx.x;
    int tid = threadIdx.x;
    int nsel = nselArr[bc];
    const ull* mrow = mask + ((size_t)bc * ROWS << 4);

    __shared__ ull sm[2048];                // 2 x (64 rows x 16 words) = 16 KB
    __shared__ ull kw[WORDS];
    __shared__ unsigned pref[WORDS + 1];

    if (tid < 64) {                          // wave 0: serial reduce
        int lane = tid;
        int nchunk = (nsel + 63) >> 6;       // <= 16
        ull S = 0ull;
        int g = lane >> 4;
        int w = lane & 15;

        ull ra[16], rb[16];
        if (nchunk > 0) {
            #pragma unroll
            for (int k = 0; k < 16; ++k) ra[k] = mrow[k * 64 + lane];
            if (nchunk > 1) {
                #pragma unroll
                for (int k = 0; k < 16; ++k) rb[k] = mrow[1024 + k * 64 + lane];
            }
            #pragma unroll
            for (int k = 0; k < 16; ++k) sm[k * 64 + lane] = ra[k];

            #pragma unroll 1
            for (int cc = 0; cc < 8; ++cc) {
                int c0 = cc << 1;
                if (c0 >= nchunk) break;
                nms_chunk_body(c0, nchunk, lane, g, w, mrow, sm, ra, rb, S);
                int c1 = c0 + 1;
                if (c1 >= nchunk) break;
                nms_chunk_body(c1, nchunk, lane, g, w, mrow, sm, rb, ra, S);
            }
        }

        if (lane < WORDS) {
            int base_i = lane << 6;
            ull valid = 0ull;
            int rem = nsel - base_i;
            if (rem > 0) valid = (rem >= 64) ? ~0ull : ((1ull << rem) - 1ull);
            kw[lane] = (~S) & valid;
        }
    }
    __syncthreads();

    if (tid == 0) {
        unsigned c = 0;
        for (int w = 0; w < WORDS; ++w) { pref[w] = c; c += (unsigned)__popcll(kw[w]); }
        pref[WORDS] = c;
    }
    __syncthreads();
    unsigned tot = pref[WORDS];

    const float* rbase = rows + (size_t)bc * KTOP * 5;
    float* obase = out + (size_t)bc * KTOP * 5;
    for (int r = tid; r < KTOP; r += 256) {
        ull wv = kw[r >> 6];
        if ((wv >> (r & 63)) & 1ull) {
            int pos = (int)pref[r >> 6] + __popcll(wv & ((1ull << (r & 63)) - 1ull));
            const float* rr = rbase + r * 5;
            float* oo = obase + pos * 5;
            oo[0] = rr[0]; oo[1] = rr[1]; oo[2] = rr[2]; oo[3] = rr[3]; oo[4] = rr[4];
        }
        if (r >= (int)tot) {                 // zero-fill tail (replaces out memset)
            float* oo = obase + r * 5;
            oo[0] = 0.f; oo[1] = 0.f; oo[2] = 0.f; oo[3] = 0.f; oo[4] = 0.f;
        }
    }
}

// ------------------------------- launcher -------------------------------
extern "C" void kernel_launch(void* const* d_in, const int* in_sizes, int n_in,
                              void* d_out, int out_size, void* d_ws, size_t ws_size,
                              hipStream_t stream) {
    (void)n_in; (void)out_size; (void)ws_size;
    const float* loc   = (const float*)d_in[0];
    const float* conf  = (const float*)d_in[1];
    const float* prior = (const float*)d_in[2];
    const float* cth   = (const float*)d_in[3];
    const float* nth   = (const float*)d_in[4];
    float* out = (float*)d_out;

    int P   = in_sizes[2] / 4;
    int B   = in_sizes[0] / (4 * P);
    int C   = in_sizes[1] / (B * P);
    int Cfg = C - 1;
    int NBC = B * Cfg;

    // ---- carve workspace (256B aligned sections; widest types first) ----
    char* base = (char*)d_ws;
    size_t off = 0;
    auto carve = [&](size_t bytes) { char* p = base + off; off = (off + bytes + 255) & ~(size_t)255; return p; };

    float4*   pbox   = (float4*)  carve((size_t)NBC * ROWS * 16);
    ull*      cand   = (ull*)     carve((size_t)NBC * CAP * 8);
    ull*      mask   = (ull*)     carve((size_t)NBC * ROWS * WORDS * 8);
    float*    scores = (float*)   carve((size_t)NBC * P * 4);
    float*    rows   = (float*)   carve((size_t)NBC * KTOP * 5 * 4);
    float*    bar    = (float*)   carve((size_t)NBC * ROWS * 4);
    unsigned* hist   = (unsigned*)carve((size_t)NBC * NB2 * 4 + (size_t)NBC * 4); // hist + cnt
    unsigned* cnt    = hist + (size_t)NBC * NB2;
    unsigned* pivot  = (unsigned*)carve((size_t)NBC * 4);
    int*      nselA  = (int*)     carve((size_t)NBC * 4);

    int histW = NBC * NB2 + NBC;             // words to zero (hist + cnt)

    int GYH = (P + HCH4 - 1) / HCH4;         // hist chunks (float4-aligned starts)
    int GY = (P + GSTAGE - 1) / GSTAGE;      // gather chunks: chunk <= GSTAGE guaranteed
    if (GY < 32) GY = 32;

    int n1 = B * P;
    decode_kernel<<<(n1 + 255) / 256, 256, 0, stream>>>(conf, scores, hist, histW, B, C, P);
    hist_kernel<<<dim3(NBC, GYH), 256, 0, stream>>>(scores, cth, hist, P);
    gather_kernel<<<dim3(NBC, GY), 256, 0, stream>>>(scores, hist, pivot, cnt, cand, cth, P);
    sort_kernel<<<NBC, 1024, 0, stream>>>(cand, cnt, pivot, loc, prior, rows, pbox, bar, nselA, P, Cfg);
    mask_kernel<<<dim3(NBC, ROWS / 64), 1024, 0, stream>>>(pbox, bar, nselA, nth, mask);
    reduce_pack_kernel<<<NBC, 256, 0, stream>>>(mask, nselA, rows, out);
}